// Round 5
// baseline (420.376 us; speedup 1.0000x reference)
//
#include <hip/hip_runtime.h>

// OHEM loss: exact k-th order statistic via 20-bit histogram select + pair
// resolution, fused log-softmax NLL, masked mean.  3 launches:
//   init   : zero Ctrl + hist20 (4MB)
//   row    : pred (256MB) via LDS tiles -> keys, nll, hist8 (LDS-aggregated),
//            hist20 (plain scattered atomics, positives skipped), pos_num
//   reduceF: block-redundant select (byte3 from hist8, 12 more bits from the
//            hist20 slice) -> stream keys/label/nll; definite rows to reg
//            sum/cnt; equal-top20 rows appended as (low12,nll) pairs;
//            last-done block resolves low 12 bits from pairs and writes loss.

typedef float f4 __attribute__((ext_vector_type(4)));

#define TILE_ROWS 256
#define ROW_F4    9   // 8 data f4 + 1 pad f4 -> conflict-reduced LDS b128 r/w

struct Ctrl {
    unsigned hist8[256];
    unsigned pos_num;
    unsigned cnt;
    unsigned done;
    unsigned pair_cnt;
    double   sum;
};

// ws layout: [Ctrl pad 4KB][hist20 4MB][keys n*4][nll n*4][pairs n*8]
#define HIST20_OFF  4096
#define HIST20_SZ   (1u << 20)

__global__ void init_kernel(unsigned* w, int words) {
    for (int i = threadIdx.x + blockIdx.x * blockDim.x; i < words;
         i += blockDim.x * gridDim.x)
        w[i] = 0u;
}

// Wave-aggregated LDS histogram add (top byte has few distinct values).
__device__ inline void wave_hist_add(unsigned* h, unsigned bucket) {
    unsigned long long todo = __ballot(1);
    while (todo) {
        int leader = (int)__builtin_ctzll(todo);
        unsigned b = __shfl(bucket, leader);
        unsigned long long same = __ballot(bucket == b) & todo;
        if ((int)(threadIdx.x & 63) == leader)
            atomicAdd(&h[b], (unsigned)__popcll(same));
        todo &= ~same;
    }
}

__global__ void __launch_bounds__(256)
row_kernel(const f4* __restrict__ pred4, const int* __restrict__ label,
           unsigned* __restrict__ keys, float* __restrict__ nll,
           unsigned* __restrict__ hist20, Ctrl* __restrict__ c, int n) {
    __shared__ f4 tile[TILE_ROWS * ROW_F4];   // 36 KB
    __shared__ unsigned h[256];
    for (int i = threadIdx.x; i < 256; i += 256) h[i] = 0u;
    __syncthreads();

    const int tid = threadIdx.x;
    int pos_local = 0;
    const int tile_stride = gridDim.x * TILE_ROWS;

    for (int tbase = blockIdx.x * TILE_ROWS; tbase < n; tbase += tile_stride) {
        // stage 256 rows x 128B, fully coalesced (4KB per instruction)
#pragma unroll
        for (int k = 0; k < 8; ++k) {
            int idx = (k << 8) + tid;                 // 0..2047
            f4 v = pred4[(size_t)tbase * 8 + idx];
            tile[(idx >> 3) * ROW_F4 + (idx & 7)] = v;
        }
        __syncthreads();

        int row = tbase + tid;
        float r[32];
#pragma unroll
        for (int j = 0; j < 8; ++j) {
            f4 v = tile[tid * ROW_F4 + j];
            r[4 * j + 0] = v.x; r[4 * j + 1] = v.y;
            r[4 * j + 2] = v.z; r[4 * j + 3] = v.w;
        }
        float m_nb = r[1];
#pragma unroll
        for (int j = 2; j < 32; ++j) m_nb = fmaxf(m_nb, r[j]);
        float m_all = fmaxf(m_nb, r[0]);

        float s = 0.f;
#pragma unroll
        for (int j = 0; j < 32; ++j) s += __expf(r[j] - m_all);

        int lab = label[row];
        int sl = lab; sl = sl < 0 ? 0 : sl; sl = sl > 31 ? 31 : sl;
        float xl = r[0];
#pragma unroll
        for (int j = 1; j < 32; ++j) xl = (j == sl) ? r[j] : xl;

        nll[row] = (m_all + __logf(s)) - xl;

        bool is_pos = (lab != 0);
        pos_local += is_pos ? 1 : 0;

        float ns = is_pos ? -__builtin_inff() : m_nb;
        unsigned u    = __float_as_uint(ns);
        unsigned ukey = (u & 0x80000000u) ? ~u : (u | 0x80000000u);
        unsigned dkey = ~ukey;                 // ascending dkey = descending float
        keys[row] = dkey;
        wave_hist_add(h, dkey >> 24);
        if (!is_pos) atomicAdd(&hist20[dkey >> 12], 1u);  // negatives spread wide

        __syncthreads();   // protect tile before next stage
    }

#pragma unroll
    for (int off = 32; off > 0; off >>= 1) pos_local += __shfl_down(pos_local, off);
    __shared__ int wsum[4];
    int wid = threadIdx.x >> 6;
    if ((threadIdx.x & 63) == 0) wsum[wid] = pos_local;
    __syncthreads();
    if (threadIdx.x == 0)
        atomicAdd(&c->pos_num, (unsigned)(wsum[0] + wsum[1] + wsum[2] + wsum[3]));

    for (int i = threadIdx.x; i < 256; i += 256)
        if (h[i]) atomicAdd(&c->hist8[i], h[i]);
}

__global__ void __launch_bounds__(256)
reduceF_kernel(const unsigned* __restrict__ keys, const int* __restrict__ label,
               const float* __restrict__ nll, const unsigned* __restrict__ hist20,
               unsigned long long* __restrict__ pairs, Ctrl* __restrict__ c,
               const int* __restrict__ factor_p, int n, float* __restrict__ out) {
    __shared__ unsigned s[256];
    __shared__ unsigned shb, shr;
    const int t = threadIdx.x;
    const int lane = t & 63;

    long long pos     = (long long)c->pos_num;
    long long neg_sum = pos * (long long)factor_p[0];
    long long num_neg = (long long)n - pos;
    long long idx     = neg_sum - 1;
    if (idx < 0) idx = 0;
    if (idx > (long long)n - 1) idx = (long long)n - 1;
    const bool use_thr = (num_neg > neg_sum);

    unsigned prefix20 = 0u, rank2 = 0u;
    if (use_thr) {
        // --- select byte3 from hist8
        unsigned rank = (unsigned)idx;
        unsigned cnt8 = c->hist8[t];
        s[t] = cnt8;
        __syncthreads();
#pragma unroll
        for (int off = 1; off < 256; off <<= 1) {
            unsigned v = (t >= off) ? s[t - off] : 0u;
            __syncthreads();
            s[t] += v;
            __syncthreads();
        }
        unsigned incl = s[t], excl = incl - cnt8;
        if (cnt8 > 0u && excl <= rank && rank < incl) {
            shb = (unsigned)t;
            shr = rank - excl;
        }
        __syncthreads();
        unsigned b3 = shb;
        unsigned rank1 = shr;
        __syncthreads();

        // --- select 12 more bits from the hist20 slice for byte3
        const unsigned* slice = hist20 + ((size_t)b3 << 12);
        unsigned lc[16]; unsigned lsum = 0u;
#pragma unroll
        for (int i = 0; i < 16; ++i) { lc[i] = slice[t * 16 + i]; lsum += lc[i]; }
        s[t] = lsum;
        __syncthreads();
#pragma unroll
        for (int off = 1; off < 256; off <<= 1) {
            unsigned v = (t >= off) ? s[t - off] : 0u;
            __syncthreads();
            s[t] += v;
            __syncthreads();
        }
        unsigned incl2 = s[t], excl2 = incl2 - lsum;
        if (lsum > 0u && excl2 <= rank1 && rank1 < incl2) {
            unsigned r = rank1 - excl2;
#pragma unroll
            for (int i = 0; i < 16; ++i) {
                if (r < lc[i]) { shb = (unsigned)(t * 16 + i); shr = r; break; }
                r -= lc[i];
            }
        }
        __syncthreads();
        prefix20 = (b3 << 12) | shb;
        rank2 = shr;
        __syncthreads();
    }

    // --- stream all rows
    double local = 0.0;
    int cntl = 0;
    const int stride = gridDim.x * blockDim.x;
    for (int i = blockIdx.x * blockDim.x + t; i < n; i += stride) {
        int lab = label[i];
        float nl = nll[i];
        bool doapp = false;
        unsigned k = 0u;
        if (use_thr) {
            k = keys[i];
            unsigned top20 = k >> 12;
            bool is_pos = (lab != 0);
            if (is_pos || top20 < prefix20) { local += (double)nl; cntl++; }
            else if (top20 == prefix20) doapp = true;
        } else {
            if (lab != -1) { local += (double)nl; cntl++; }
        }
        unsigned long long m = __ballot(doapp);
        if (doapp) {
            int lead = (int)__builtin_ctzll(m);
            unsigned base = 0u;
            if (lane == lead) base = atomicAdd(&c->pair_cnt, (unsigned)__popcll(m));
            base = __shfl(base, lead);
            unsigned off = (unsigned)__popcll(m & ((1ull << lane) - 1ull));
            pairs[base + off] =
                ((unsigned long long)(k & 0xFFFu) << 32) |
                (unsigned long long)__float_as_uint(nl);
        }
    }
#pragma unroll
    for (int off = 32; off > 0; off >>= 1) {
        local += __shfl_down(local, off);
        cntl  += __shfl_down(cntl, off);
    }
    __shared__ double sd[4];
    __shared__ int    si[4];
    int wid = t >> 6;
    if (lane == 0) { sd[wid] = local; si[wid] = cntl; }
    __syncthreads();
    __shared__ int s_last;
    if (t == 0) {
        atomicAdd(&c->sum, sd[0] + sd[1] + sd[2] + sd[3]);
        atomicAdd(&c->cnt, (unsigned)(si[0] + si[1] + si[2] + si[3]));
        __threadfence();
        unsigned d = atomicAdd(&c->done, 1u);
        s_last = (d == gridDim.x - 1) ? 1 : 0;
    }
    __syncthreads();
    if (!s_last) return;

    // --- last block: resolve low 12 bits from pairs, write loss
    __threadfence();
    __shared__ unsigned pc[4096];   // 16KB
    __shared__ float    ps[4096];   // 16KB
    __shared__ double   fssum;
    __shared__ unsigned fscnt;
    if (t == 0) { fssum = 0.0; fscnt = 0u; }

    if (use_thr) {
        for (int i = t; i < 4096; i += 256) { pc[i] = 0u; ps[i] = 0.f; }
        __syncthreads();
        unsigned M = c->pair_cnt;
        for (unsigned j = t; j < M; j += 256) {
            unsigned long long p = pairs[j];
            unsigned b = (unsigned)(p >> 32);
            atomicAdd(&pc[b], 1u);
            atomicAdd(&ps[b], __uint_as_float((unsigned)p));
        }
        __syncthreads();
        // select b* (12-bit) where rank2 falls
        unsigned lc2[16]; unsigned lsum = 0u;
#pragma unroll
        for (int i = 0; i < 16; ++i) { lc2[i] = pc[t * 16 + i]; lsum += lc2[i]; }
        s[t] = lsum;
        __syncthreads();
#pragma unroll
        for (int off = 1; off < 256; off <<= 1) {
            unsigned v = (t >= off) ? s[t - off] : 0u;
            __syncthreads();
            s[t] += v;
            __syncthreads();
        }
        unsigned incl = s[t], excl = incl - lsum;
        if (lsum > 0u && excl <= rank2 && rank2 < incl) {
            unsigned r = rank2 - excl;
#pragma unroll
            for (int i = 0; i < 16; ++i) {
                if (r < lc2[i]) { shb = (unsigned)(t * 16 + i); break; }
                r -= lc2[i];
            }
        }
        __syncthreads();
        unsigned bstar = shb;
        // include every pair bucket <= b* (ties at threshold all pass mask)
        double fsl = 0.0; unsigned fcl = 0u;
        for (int i = t; i < 4096; i += 256)
            if ((unsigned)i <= bstar) { fcl += pc[i]; fsl += (double)ps[i]; }
#pragma unroll
        for (int off = 32; off > 0; off >>= 1) {
            fsl += __shfl_down(fsl, off);
            fcl += __shfl_down(fcl, off);
        }
        if (lane == 0) { sd[wid] = fsl; si[wid] = (int)fcl; }
        __syncthreads();
        if (t == 0) {
            fssum = sd[0] + sd[1] + sd[2] + sd[3];
            fscnt = (unsigned)(si[0] + si[1] + si[2] + si[3]);
        }
        __syncthreads();
    }
    if (t == 0) {
        double sum = c->sum + fssum;
        unsigned ctn = c->cnt + fscnt;
        double denom = (ctn == 0u) ? 1.0 : (double)ctn;
        out[0] = (float)(sum / denom);
    }
}

extern "C" void kernel_launch(void* const* d_in, const int* in_sizes, int n_in,
                              void* d_out, int out_size, void* d_ws, size_t ws_size,
                              hipStream_t stream) {
    const float* pred = (const float*)d_in[0];
    const int* label  = (const int*)d_in[1];
    const int* factor = (const int*)d_in[2];
    int n = in_sizes[1];
    float* out = (float*)d_out;

    char* ws = (char*)d_ws;
    Ctrl* c = (Ctrl*)ws;
    unsigned* hist20 = (unsigned*)(ws + HIST20_OFF);
    unsigned* keys = (unsigned*)(ws + HIST20_OFF + HIST20_SZ * 4);
    float* nll = (float*)(ws + HIST20_OFF + HIST20_SZ * 4 + (size_t)n * 4);
    unsigned long long* pairs =
        (unsigned long long*)(ws + HIST20_OFF + HIST20_SZ * 4 + (size_t)n * 8);

    int zwords = (int)((HIST20_OFF + HIST20_SZ * 4) / 4);
    init_kernel<<<1024, 256, 0, stream>>>((unsigned*)ws, zwords);
    row_kernel<<<2048, 256, 0, stream>>>((const f4*)pred, label, keys, nll,
                                         hist20, c, n);
    reduceF_kernel<<<1024, 256, 0, stream>>>(keys, label, nll, hist20, pairs,
                                             c, factor, n, out);
}

// Round 7
// 144.583 us; speedup vs baseline: 2.9075x; 2.9075x over previous
//
#include <hip/hip_runtime.h>

// OHEM loss: exact k-th order statistic via 8+12-bit radix select on a
// monotonic key, fused log-softmax NLL, masked mean.  4 dispatches:
//   init   : zero Ctrl (~50KB)
//   row    : pred (256MB) via 256-row LDS tiles -> keys, nll, hist8
//            (wave-aggregated top byte), pos_num          [round-4 validated]
//   hist12 : block-redundant byte-3 select + filtered 12-bit LDS histogram
//            (bits 23..12) -> global hist12[4096]
//   reduceF: select 20-bit prefix (scan hist8 + hist12); stream keys/label/
//            nll; definite rows -> reg sum/cnt; equal-top20 rows -> 4096
//            global byte-buckets; last-done block resolves low 12 bits and
//            writes the loss                               [r5-validated done-counter]

typedef float f4 __attribute__((ext_vector_type(4)));

#define TILE_ROWS 256
#define ROW_F4    9   // 8 data f4 + 1 pad f4 -> conflict-free LDS b128 r/w

struct Ctrl {
    unsigned hist8[256];
    unsigned hist12[4096];
    unsigned bcnt[4096];     // low-12 counts within selected 20-bit prefix
    float    bsum[4096];     // nll sums per low-12 bucket
    unsigned pos_num;
    unsigned cnt;
    unsigned done;
    unsigned pad;
    double   sum;
};

__global__ void init_kernel(unsigned* w, int words) {
    for (int i = threadIdx.x + blockIdx.x * blockDim.x; i < words;
         i += blockDim.x * gridDim.x)
        w[i] = 0u;
}

// Wave-aggregated LDS histogram add (top byte has few distinct values).
__device__ inline void wave_hist_add(unsigned* h, unsigned bucket) {
    unsigned long long todo = __ballot(1);
    while (todo) {
        int leader = (int)__builtin_ctzll(todo);
        unsigned b = __shfl(bucket, leader);
        unsigned long long same = __ballot(bucket == b) & todo;
        if ((int)(threadIdx.x & 63) == leader)
            atomicAdd(&h[b], (unsigned)__popcll(same));
        todo &= ~same;
    }
}

__global__ void __launch_bounds__(256)
row_kernel(const f4* __restrict__ pred4, const int* __restrict__ label,
           unsigned* __restrict__ keys, float* __restrict__ nll,
           Ctrl* __restrict__ c, int n) {
    __shared__ f4 tile[TILE_ROWS * ROW_F4];   // 36 KB
    __shared__ unsigned h[256];
    for (int i = threadIdx.x; i < 256; i += 256) h[i] = 0u;
    __syncthreads();

    const int tid = threadIdx.x;
    int pos_local = 0;
    const int tile_stride = gridDim.x * TILE_ROWS;

    for (int tbase = blockIdx.x * TILE_ROWS; tbase < n; tbase += tile_stride) {
        // stage 256 rows x 128B, fully coalesced (4KB per instruction)
#pragma unroll
        for (int k = 0; k < 8; ++k) {
            int idx = (k << 8) + tid;                 // 0..2047
            f4 v = pred4[(size_t)tbase * 8 + idx];
            tile[(idx >> 3) * ROW_F4 + (idx & 7)] = v;
        }
        __syncthreads();

        int row = tbase + tid;
        float r[32];
#pragma unroll
        for (int j = 0; j < 8; ++j) {
            f4 v = tile[tid * ROW_F4 + j];
            r[4 * j + 0] = v.x; r[4 * j + 1] = v.y;
            r[4 * j + 2] = v.z; r[4 * j + 3] = v.w;
        }
        float m_nb = r[1];
#pragma unroll
        for (int j = 2; j < 32; ++j) m_nb = fmaxf(m_nb, r[j]);
        float m_all = fmaxf(m_nb, r[0]);

        float s = 0.f;
#pragma unroll
        for (int j = 0; j < 32; ++j) s += __expf(r[j] - m_all);

        int lab = label[row];
        int sl = lab; sl = sl < 0 ? 0 : sl; sl = sl > 31 ? 31 : sl;
        float xl = r[0];
#pragma unroll
        for (int j = 1; j < 32; ++j) xl = (j == sl) ? r[j] : xl;

        nll[row] = (m_all + __logf(s)) - xl;

        bool is_pos = (lab != 0);
        pos_local += is_pos ? 1 : 0;

        float ns = is_pos ? -__builtin_inff() : m_nb;
        unsigned u    = __float_as_uint(ns);
        unsigned ukey = (u & 0x80000000u) ? ~u : (u | 0x80000000u);
        unsigned dkey = ~ukey;                 // ascending dkey = descending float
        keys[row] = dkey;
        wave_hist_add(h, dkey >> 24);

        __syncthreads();   // protect tile before next stage
    }

#pragma unroll
    for (int off = 32; off > 0; off >>= 1) pos_local += __shfl_down(pos_local, off);
    __shared__ int wsum[4];
    int wid = threadIdx.x >> 6;
    if ((threadIdx.x & 63) == 0) wsum[wid] = pos_local;
    __syncthreads();
    if (threadIdx.x == 0)
        atomicAdd(&c->pos_num, (unsigned)(wsum[0] + wsum[1] + wsum[2] + wsum[3]));

    for (int i = threadIdx.x; i < 256; i += 256)
        if (h[i]) atomicAdd(&c->hist8[i], h[i]);
}

// 256-wide inclusive scan of s[] in LDS (blockDim.x == 256).
__device__ inline void block_scan256(unsigned* s) {
    const int t = threadIdx.x;
#pragma unroll
    for (int off = 1; off < 256; off <<= 1) {
        unsigned v = (t >= off) ? s[t - off] : 0u;
        __syncthreads();
        s[t] += v;
        __syncthreads();
    }
}

// Rank for the k-th order statistic (clamped), shared by all kernels.
__device__ inline void rank_params(const Ctrl* c, int factor, int n,
                                   unsigned& rank, bool& use_thr) {
    long long pos     = (long long)c->pos_num;
    long long neg_sum = pos * (long long)factor;
    long long num_neg = (long long)n - pos;
    long long idx     = neg_sum - 1;
    if (idx < 0) idx = 0;
    if (idx > (long long)n - 1) idx = (long long)n - 1;
    rank    = (unsigned)idx;
    use_thr = (num_neg > neg_sum);
}

// Select byte 3 from hist8 (block-redundant). Returns b3, residual rank.
__device__ inline void select_byte3(const Ctrl* c, unsigned rank, unsigned* s,
                                    unsigned* shbr, unsigned& b3, unsigned& rank1) {
    const int t = threadIdx.x;
    unsigned cnt8 = c->hist8[t];
    s[t] = cnt8;
    __syncthreads();
    block_scan256(s);
    unsigned incl = s[t], excl = incl - cnt8;
    if (cnt8 > 0u && excl <= rank && rank < incl) {
        shbr[0] = (unsigned)t;
        shbr[1] = rank - excl;
    }
    __syncthreads();
    b3 = shbr[0];
    rank1 = shbr[1];
    __syncthreads();
}

// Select 12 bits from a 4096-bin histogram (block-redundant).
__device__ inline void select_12(const unsigned* hist, unsigned rank_in,
                                 unsigned* s, unsigned* shbr,
                                 unsigned& sub, unsigned& rank_out) {
    const int t = threadIdx.x;
    unsigned lc[16]; unsigned lsum = 0u;
#pragma unroll
    for (int i = 0; i < 16; ++i) { lc[i] = hist[t * 16 + i]; lsum += lc[i]; }
    s[t] = lsum;
    __syncthreads();
    block_scan256(s);
    unsigned incl = s[t], excl = incl - lsum;
    if (lsum > 0u && excl <= rank_in && rank_in < incl) {
        unsigned r = rank_in - excl;
#pragma unroll
        for (int i = 0; i < 16; ++i) {
            if (r < lc[i]) { shbr[0] = (unsigned)(t * 16 + i); shbr[1] = r; break; }
            r -= lc[i];
        }
    }
    __syncthreads();
    sub = shbr[0];
    rank_out = shbr[1];
    __syncthreads();
}

__global__ void __launch_bounds__(256)
hist12_kernel(const unsigned* __restrict__ keys, Ctrl* __restrict__ c,
              const int* __restrict__ factor_p, int n) {
    __shared__ unsigned s[256];
    __shared__ unsigned shbr[2];
    __shared__ unsigned h[4096];   // 16 KB
    const int t = threadIdx.x;

    unsigned rank; bool use_thr;
    rank_params(c, factor_p[0], n, rank, use_thr);
    unsigned b3, rank1;
    select_byte3(c, rank, s, shbr, b3, rank1);

    for (int i = t; i < 4096; i += 256) h[i] = 0u;
    __syncthreads();

    const int stride = gridDim.x * blockDim.x;
    for (int i = blockIdx.x * blockDim.x + t; i < n; i += stride) {
        unsigned k = keys[i];
        if ((k >> 24) == b3) atomicAdd(&h[(k >> 12) & 0xFFFu], 1u);
    }
    __syncthreads();
    for (int i = t; i < 4096; i += 256)
        if (h[i]) atomicAdd(&c->hist12[i], h[i]);
}

__global__ void __launch_bounds__(256)
reduceF_kernel(const unsigned* __restrict__ keys, const int* __restrict__ label,
               const float* __restrict__ nll, Ctrl* __restrict__ c,
               const int* __restrict__ factor_p, int n, float* __restrict__ out) {
    __shared__ unsigned s[256];
    __shared__ unsigned shbr[2];
    __shared__ double sd[4];
    __shared__ int    si[4];
    const int t = threadIdx.x, lane = t & 63, wid = t >> 6;

    unsigned rank; bool use_thr;
    rank_params(c, factor_p[0], n, rank, use_thr);
    unsigned b3, rank1;
    select_byte3(c, rank, s, shbr, b3, rank1);
    unsigned sub, rank2;
    select_12(c->hist12, rank1, s, shbr, sub, rank2);
    const unsigned prefix20 = (b3 << 12) | sub;

    // ---- stream all rows
    double local = 0.0;
    int cntl = 0;
    const int stride = gridDim.x * blockDim.x;
    for (int i = blockIdx.x * blockDim.x + t; i < n; i += stride) {
        int lab = label[i];
        float nl = nll[i];
        if (use_thr) {
            unsigned k = keys[i];
            unsigned top20 = k >> 12;
            if (lab != 0 || top20 < prefix20) { local += (double)nl; cntl++; }
            else if (top20 == prefix20) {
                atomicAdd(&c->bcnt[k & 0xFFFu], 1u);
                atomicAdd(&c->bsum[k & 0xFFFu], nl);
            }
        } else {
            if (lab != -1) { local += (double)nl; cntl++; }
        }
    }
#pragma unroll
    for (int off = 32; off > 0; off >>= 1) {
        local += __shfl_down(local, off);
        cntl  += __shfl_down(cntl, off);
    }
    if (lane == 0) { sd[wid] = local; si[wid] = cntl; }
    __syncthreads();
    __shared__ int s_last;
    if (t == 0) {
        atomicAdd(&c->sum, sd[0] + sd[1] + sd[2] + sd[3]);
        atomicAdd(&c->cnt, (unsigned)(si[0] + si[1] + si[2] + si[3]));
        __threadfence();
        unsigned d = atomicAdd(&c->done, 1u);
        s_last = (d == gridDim.x - 1) ? 1 : 0;
    }
    __syncthreads();
    if (!s_last) return;

    // ---- last block: resolve low 12 bits from buckets, write loss
    __threadfence();
    __shared__ double   fssum;
    __shared__ unsigned fscnt;
    if (t == 0) { fssum = 0.0; fscnt = 0u; }
    __syncthreads();
    if (use_thr) {
        unsigned bstar, dummy;
        select_12(c->bcnt, rank2, s, shbr, bstar, dummy);
        // include every bucket <= bstar (ties at the threshold all pass mask)
        double fsl = 0.0; unsigned fcl = 0u;
        for (int i = t; i < 4096; i += 256)
            if ((unsigned)i <= bstar) { fcl += c->bcnt[i]; fsl += (double)c->bsum[i]; }
#pragma unroll
        for (int off = 32; off > 0; off >>= 1) {
            fsl += __shfl_down(fsl, off);
            fcl += __shfl_down(fcl, off);
        }
        if (lane == 0) { sd[wid] = fsl; si[wid] = (int)fcl; }
        __syncthreads();
        if (t == 0) {
            fssum = sd[0] + sd[1] + sd[2] + sd[3];
            fscnt = (unsigned)(si[0] + si[1] + si[2] + si[3]);
        }
        __syncthreads();
    }
    if (t == 0) {
        double sm = c->sum + fssum;
        unsigned ctn = c->cnt + fscnt;
        double denom = (ctn == 0u) ? 1.0 : (double)ctn;
        out[0] = (float)(sm / denom);
    }
}

extern "C" void kernel_launch(void* const* d_in, const int* in_sizes, int n_in,
                              void* d_out, int out_size, void* d_ws, size_t ws_size,
                              hipStream_t stream) {
    const float* pred = (const float*)d_in[0];
    const int* label  = (const int*)d_in[1];
    const int* factor = (const int*)d_in[2];
    int n = in_sizes[1];
    float* out = (float*)d_out;

    char* ws = (char*)d_ws;
    Ctrl* c = (Ctrl*)ws;
    unsigned* keys = (unsigned*)(ws + 65536);
    float* nll = (float*)(ws + 65536 + (size_t)n * 4);

    init_kernel<<<64, 256, 0, stream>>>((unsigned*)c, (int)(sizeof(Ctrl) / 4));
    row_kernel<<<2048, 256, 0, stream>>>((const f4*)pred, label, keys, nll, c, n);
    hist12_kernel<<<1024, 256, 0, stream>>>(keys, c, factor, n);
    reduceF_kernel<<<1024, 256, 0, stream>>>(keys, label, nll, c, factor, n, out);
}